// Round 5
// baseline (235.561 us; speedup 1.0000x reference)
//
#include <hip/hip_runtime.h>
#include <hip/hip_bf16.h>

// Problem constants (from reference)
#define P_TOTAL 16384      // H*W pixels
#define KN      16         // kernels per pixel
#define CK      144        // in_channel * kernel_size
#define BATCH   8
#define IMG     262144     // C*H*W
#define NP      8          // pixels per block
#define NCHUNK  (P_TOTAL / NP)   // 2048 blocks

// Session ledger:
//  - ~176 us of dur_us is unconditional harness tax (2x 576 MB d_ws poison fills).
//  - R3: nt-load on read-once streams NEUTRAL (L2-thrash theory dead).
//  - R4: 8-pixel pipeline NEUTRAL (compiler drains vmcnt(0) at every s_barrier ->
//    no cross-barrier in-flight loads at HIP level; TLP already covered latency).
//  - R5 theory: kernel is LDS-PIPE-bound: 18 b128 reads + 16 ds_swizzle per thread
//    per pixel ~= 1350-1700 cyc/pixel/CU ~= the whole kernel time.
//    Fix: keep patch in bf16 (16B/row): 9 b128 reads instead of 18, raw b128
//    gather fill (no cvt), unpack at compute via 1 bit-op/elem (VALU is 8% busy).

__device__ __forceinline__ float blo16(uint32_t u) {
    union { uint32_t i; float f; } v; v.i = u << 16;        return v.f;
}
__device__ __forceinline__ float bhi16(uint32_t u) {
    union { uint32_t i; float f; } v; v.i = u & 0xffff0000u; return v.f;
}

// ---------------- transpose+quantize: x[b][id] (f32) -> xt[id][b] (bf16) ----------------
__global__ __launch_bounds__(256) void transpose_x_bf16(
    const float* __restrict__ x, float4* __restrict__ xt)
{
    const int i = blockIdx.x * 256 + threadIdx.x;   // id in [0, IMG)
    union { __hip_bfloat16 h[8]; float4 f4; } u;
#pragma unroll
    for (int b = 0; b < BATCH; ++b)
        u.h[b] = __float2bfloat16(
            __builtin_nontemporal_load(&x[(size_t)b * IMG + i]));  // read-once stream
    xt[i] = u.f4;
}

// ---------------- main kernel: bf16 LDS patch ----------------
__global__ __launch_bounds__(256) void abc2d_xt_bf16lds(
    const float4* __restrict__ xt,    // bf16x8 [IMG]
    const float*  __restrict__ w,     // [P, KN, CK]
    const int*    __restrict__ hidx,  // [P, CK]
    float* __restrict__ out)          // [B, KN, P]
{
    __shared__ float4 patchv[2][CK];                // bf16x8 rows, 2 x 2304 B
    __shared__ float  outbuf[KN * BATCH * NP];      // 4 kB staged output

    // XCD swizzle over 2048 chunks (2048 % 8 == 0 -> bijective)
    const int bid   = blockIdx.x;
    const int chunk = (bid & 7) * (NCHUNK / 8) + (bid >> 3);
    const int p0    = chunk * NP;
    const int t     = threadIdx.x;
    const int k     = t >> 4;
    const int cs    = t & 15;
    const bool do_g = (t < CK);

    float wcur[9], wnxt[9];
    float4 g;                 // gathered bf16x8 row for the current pixel
    int id_nxt = 0;

    // ---------------- prologue ----------------
    {
        const float* wp = w + (size_t)p0 * (KN * CK) + (size_t)k * CK + cs;
#pragma unroll
        for (int i = 0; i < 9; ++i)
            wcur[i] = __builtin_nontemporal_load(wp + 16 * i);
    }
    if (do_g) {
        const int id0 = hidx[p0 * CK + t];
        g = xt[id0];
        id_nxt = hidx[(p0 + 1) * CK + t];
    }

    // ---------------- per-pixel loop ----------------
#pragma unroll
    for (int j = 0; j < NP; ++j) {
        const int jb = j & 1;

        // issue next-pixel weight stream
        if (j + 1 < NP) {
            const float* wp = w + (size_t)(p0 + j + 1) * (KN * CK) + (size_t)k * CK + cs;
#pragma unroll
            for (int i = 0; i < 9; ++i)
                wnxt[i] = __builtin_nontemporal_load(wp + 16 * i);
        }

        // LDS fill: raw 16B bf16 row, single b128 write, no conversion
        if (do_g) patchv[jb][t] = g;
        __syncthreads();

        // issue next gather chain
        if (do_g && j + 1 < NP) {
            g = xt[id_nxt];
            if (j + 2 < NP) id_nxt = hidx[(p0 + j + 2) * CK + t];
        }

        // ---------- compute pixel j: 9 b128 reads, unpack bf16 inline ----------
        float acc[BATCH];
#pragma unroll
        for (int b = 0; b < BATCH; ++b) acc[b] = 0.f;

#pragma unroll
        for (int i = 0; i < 9; ++i) {
            const int c = cs + 16 * i;              // 4-way k-broadcast, 2-way alias: free
            const float wv = wcur[i];
            const float4 q = patchv[jb][c];
            const uint32_t d0 = __float_as_uint(q.x);
            const uint32_t d1 = __float_as_uint(q.y);
            const uint32_t d2 = __float_as_uint(q.z);
            const uint32_t d3 = __float_as_uint(q.w);
            acc[0] += wv * blo16(d0);
            acc[1] += wv * bhi16(d0);
            acc[2] += wv * blo16(d1);
            acc[3] += wv * bhi16(d1);
            acc[4] += wv * blo16(d2);
            acc[5] += wv * bhi16(d2);
            acc[6] += wv * blo16(d3);
            acc[7] += wv * bhi16(d3);
        }

        // reduce across the 16 cs lanes (xor1/2 -> DPP, xor4/8 -> ds_swizzle)
#pragma unroll
        for (int b = 0; b < BATCH; ++b) {
            float v = acc[b];
            v += __shfl_xor(v, 1);
            v += __shfl_xor(v, 2);
            v += __shfl_xor(v, 4);
            v += __shfl_xor(v, 8);
            acc[b] = v;
        }

        // stage output
        if (cs == 0) {
#pragma unroll
            for (int b = 0; b < BATCH; ++b)
                outbuf[(k * BATCH + b) * NP + j] = acc[b];
        }

        // rotate weight registers (fully unrolled -> SSA rename)
        if (j + 1 < NP) {
#pragma unroll
            for (int i = 0; i < 9; ++i) wcur[i] = wnxt[i];
        }
    }

    // ---------------- coalesced output flush: 32B per (b,k) row ----------------
    __syncthreads();
    if (t < KN * BATCH) {
        const int kk = t >> 3;
        const int bb = t & 7;
        const float* src = &outbuf[(kk * BATCH + bb) * NP];
        const float4 v0 = *reinterpret_cast<const float4*>(src);
        const float4 v1 = *reinterpret_cast<const float4*>(src + 4);
        float* dst = &out[((size_t)bb * KN + kk) * P_TOTAL + p0];
        *reinterpret_cast<float4*>(dst)     = v0;
        *reinterpret_cast<float4*>(dst + 4) = v1;
    }
}

// ---------------- fallback: direct f32 gather (no workspace) ----------------
#define PSTRIDE 12
__global__ __launch_bounds__(256) void abc2d_direct(
    const float* __restrict__ x, const float* __restrict__ w,
    const int* __restrict__ hidx, float* __restrict__ out)
{
    __shared__ float patch[CK * PSTRIDE];
    const int bid = blockIdx.x;
    const int p   = (bid & 7) * (P_TOTAL / 8) + (bid >> 3);
    const int t   = threadIdx.x;
    const int k   = t >> 4;
    const int cs  = t & 15;

    if (t < CK) {
        const int id = hidx[p * CK + t];
        float v[BATCH];
#pragma unroll
        for (int b = 0; b < BATCH; ++b) v[b] = x[(size_t)b * IMG + (size_t)id];
        float* pr = &patch[t * PSTRIDE];
        *reinterpret_cast<float4*>(pr)     = make_float4(v[0], v[1], v[2], v[3]);
        *reinterpret_cast<float4*>(pr + 4) = make_float4(v[4], v[5], v[6], v[7]);
    }

    const float* wp = w + (size_t)p * (KN * CK) + (size_t)k * CK;
    float wreg[9];
#pragma unroll
    for (int i = 0; i < 9; ++i) wreg[i] = wp[cs + 16 * i];
    __syncthreads();

    float acc[BATCH];
#pragma unroll
    for (int b = 0; b < BATCH; ++b) acc[b] = 0.f;
#pragma unroll
    for (int i = 0; i < 9; ++i) {
        const float wv = wreg[i];
        const float* pr = &patch[(cs + 16 * i) * PSTRIDE];
        const float4 q0 = *reinterpret_cast<const float4*>(pr);
        const float4 q1 = *reinterpret_cast<const float4*>(pr + 4);
        acc[0] += wv * q0.x; acc[1] += wv * q0.y; acc[2] += wv * q0.z; acc[3] += wv * q0.w;
        acc[4] += wv * q1.x; acc[5] += wv * q1.y; acc[6] += wv * q1.z; acc[7] += wv * q1.w;
    }
#pragma unroll
    for (int b = 0; b < BATCH; ++b) {
        float v = acc[b];
        v += __shfl_xor(v, 1); v += __shfl_xor(v, 2);
        v += __shfl_xor(v, 4); v += __shfl_xor(v, 8);
        acc[b] = v;
    }
    if (cs == 0) {
#pragma unroll
        for (int b = 0; b < BATCH; ++b)
            out[(size_t)b * (KN * P_TOTAL) + (size_t)k * P_TOTAL + p] = acc[b];
    }
}

extern "C" void kernel_launch(void* const* d_in, const int* in_sizes, int n_in,
                              void* d_out, int out_size, void* d_ws, size_t ws_size,
                              hipStream_t stream) {
    const float* x    = (const float*)d_in[0];   // [8,16,128,128] f32
    const float* wts  = (const float*)d_in[1];   // [16384,16,144] f32
    const int*   hidx = (const int*)d_in[2];     // [16384,144] int32
    float* out = (float*)d_out;                  // [8,16,16384] f32

    const size_t xt_bytes = (size_t)IMG * BATCH * sizeof(__hip_bfloat16);  // 4.19 MB
    if (ws_size >= xt_bytes) {
        float4* xt = (float4*)d_ws;
        transpose_x_bf16<<<IMG / 256, 256, 0, stream>>>(x, xt);
        abc2d_xt_bf16lds<<<NCHUNK, 256, 0, stream>>>(xt, wts, hidx, out);
    } else {
        abc2d_direct<<<P_TOTAL, 256, 0, stream>>>(x, wts, hidx, out);
    }
}